// Round 4
// baseline (130.962 us; speedup 1.0000x reference)
//
#include <hip/hip_runtime.h>
#include <hip/hip_bf16.h>
#include <hip/hip_fp16.h>
#include <math.h>

#define LL 1536
#define NA 14
#define TOPK 30
#define KDIM 3152          // 16 (pos) + 14*14*16 (rbf)
#define KPAD 3200
#define NCHUNK 50          // K chunks of 64

#define TOPK_BLKS 384      // 4 rows per block
#define CONV_BLKS 100
#define NODE_BLKS 384      // 4 rows per block
#define PREP_BLKS (TOPK_BLKS + CONV_BLKS + NODE_BLKS)

#define EDGE_BLKS 512      // 3 residues per block (M = 96 rows)

typedef __attribute__((ext_vector_type(8))) short bf16x8;
typedef __attribute__((ext_vector_type(4))) float f32x4;

static __device__ __forceinline__ ushort f2bf(float f) {
    union { __hip_bfloat16 h; ushort u; } v;
    v.h = __float2bfloat16(f);
    return v.u;
}

static __device__ __forceinline__ unsigned long long u64min(
    unsigned long long a, unsigned long long b) { return a < b ? a : b; }

#define ASYNC16(ldsp, gp)                                                     \
    __builtin_amdgcn_global_load_lds(                                         \
        (const __attribute__((address_space(1))) void*)(gp),                  \
        (__attribute__((address_space(3))) void*)(ldsp), 16, 0, 0)

// ---------------------------------------------------------------------------
// prep kernel: fuses top-k (+x passthrough), W_edge transpose/convert, node LN
// ---------------------------------------------------------------------------
__global__ __launch_bounds__(256) void prep_kernel(
    const float* __restrict__ x, const float* __restrict__ mask,
    const float* __restrict__ feat,
    const float* __restrict__ W_edge, ushort* __restrict__ Wt,
    const float* __restrict__ W_node, const float* __restrict__ gamma_n,
    const float* __restrict__ beta_n, const int* __restrict__ S,
    float* __restrict__ V, float* __restrict__ out_idx, float* __restrict__ out_x)
{
    __shared__ __align__(16) char sm[24576];
    const int blk = blockIdx.x;
    const int tid = threadIdx.x;

    if (blk < TOPK_BLKS) {
        // ---------------- top-30 (4 rows per block, 1 row per wave) --------
        float* ca  = (float*)sm;            // [1536*3]
        float* msk = (float*)sm + 4608;     // [1536]
        for (int t = tid; t < LL; t += 256) {
            msk[t] = mask[t];
            ca[t * 3 + 0] = x[t * 42 + 3];
            ca[t * 3 + 1] = x[t * 42 + 4];
            ca[t * 3 + 2] = x[t * 42 + 5];
        }
        __syncthreads();

        const int lane = tid & 63;
        const int i = blk * 4 + (tid >> 6);
        const float cix = ca[i * 3 + 0], ciy = ca[i * 3 + 1], ciz = ca[i * 3 + 2];
        const float mi = msk[i];

        float d[24], m2a[24];
        float lmax = 0.f;
        #pragma unroll
        for (int c = 0; c < 24; ++c) {
            int j = lane + c * 64;
            float dx = ca[j * 3 + 0] - cix;
            float dy = ca[j * 3 + 1] - ciy;
            float dz = ca[j * 3 + 2] - ciz;
            float m2 = mi * msk[j];
            float D = m2 * sqrtf(dx * dx + dy * dy + dz * dz + 1e-6f);
            d[c] = D; m2a[c] = m2;
            lmax = fmaxf(lmax, D);
        }
        #pragma unroll
        for (int m = 1; m < 64; m <<= 1) lmax = fmaxf(lmax, __shfl_xor(lmax, m));

        unsigned long long key[24];
        #pragma unroll
        for (int c = 0; c < 24; ++c) {
            float adj = d[c] + (1.f - m2a[c]) * lmax;
            key[c] = ((unsigned long long)__float_as_uint(adj) << 32)
                   | (unsigned)(lane + c * 64);
        }
        for (int t = 0; t < TOPK; ++t) {
            unsigned long long m12[12];
            #pragma unroll
            for (int c = 0; c < 12; ++c) m12[c] = u64min(key[2 * c], key[2 * c + 1]);
            #pragma unroll
            for (int c = 0; c < 6; ++c) m12[c] = u64min(m12[2 * c], m12[2 * c + 1]);
            unsigned long long best = u64min(u64min(m12[0], m12[1]),
                u64min(m12[2], u64min(m12[3], u64min(m12[4], m12[5]))));
            #pragma unroll
            for (int m = 1; m < 64; m <<= 1) best = u64min(best, __shfl_xor(best, m));
            if (lane == 0) out_idx[i * TOPK + t] = (float)(unsigned)(best & 0xffffffffu);
            #pragma unroll
            for (int c = 0; c < 24; ++c) if (key[c] == best) key[c] = ~0ull;
        }
        for (int t = lane; t < 42; t += 64) out_x[i * 42 + t] = x[i * 42 + t];

    } else if (blk < TOPK_BLKS + CONV_BLKS) {
        // ---------------- W_edge -> Wt bf16 transpose ----------------------
        int cb = blk - TOPK_BLKS;
        int k0 = (cb % 50) * 64, n0 = (cb / 50) * 64;
        float (*tile)[65] = (float (*)[65])sm;
        #pragma unroll
        for (int r = 0; r < 16; ++r) {
            int idx = r * 256 + tid;
            int kl = idx >> 6, nl = idx & 63;
            int k = k0 + kl;
            tile[nl][kl] = (k < KDIM) ? W_edge[k * 128 + n0 + nl] : 0.f;
        }
        __syncthreads();
        #pragma unroll
        for (int r = 0; r < 16; ++r) {
            int idx = r * 256 + tid;
            int nl = idx >> 6, kl = idx & 63;
            Wt[(size_t)(n0 + nl) * KPAD + k0 + kl] = f2bf(tile[nl][kl]);
        }

    } else {
        // ---------------- node features (1 row per wave) -------------------
        int nb = blk - TOPK_BLKS - CONV_BLKS;
        float* f = (float*)sm;                     // [4][128]
        const int w = tid >> 6, lane = tid & 63;
        const int i = nb * 4 + w;
        f[w * 128 + lane] = feat[i * 128 + lane];
        f[w * 128 + 64 + lane] = feat[i * 128 + 64 + lane];
        __syncthreads();
        int s = S[i];
        float a0 = W_node[s * 128 + lane];
        float a1 = W_node[s * 128 + 64 + lane];
        #pragma unroll 8
        for (int c = 0; c < 128; ++c) {
            float fc = f[w * 128 + c];
            a0 = fmaf(fc, W_node[(21 + c) * 128 + lane], a0);
            a1 = fmaf(fc, W_node[(21 + c) * 128 + 64 + lane], a1);
        }
        float ss = a0 + a1, qq = a0 * a0 + a1 * a1;
        #pragma unroll
        for (int m = 1; m < 64; m <<= 1) {
            ss += __shfl_xor(ss, m);
            qq += __shfl_xor(qq, m);
        }
        float mean = ss * (1.f / 128.f);
        float var = qq * (1.f / 128.f) - mean * mean;
        float inv = 1.f / sqrtf(var + 1e-5f);
        V[i * 128 + lane]      = (a0 - mean) * inv * gamma_n[lane] + beta_n[lane];
        V[i * 128 + 64 + lane] = (a1 - mean) * inv * gamma_n[64 + lane] + beta_n[64 + lane];
    }
}

// ---------------------------------------------------------------------------
// edge kernel: block = 3 residues (M=96 rows), C[96x128] = A[96x3200] @ Wt^T.
// A-fragments built IN REGISTERS (no LDS round-trip); dd precomputed fp16 in
// LDS with masks folded; Bs double-buffered via global_load_lds; 1 barrier
// per K-chunk. Waves: 2x2 grid of 48x64 tiles.
// ---------------------------------------------------------------------------
__global__ __launch_bounds__(256, 2) void edge_mfma_kernel(
    const float* __restrict__ x, const float* __restrict__ mask,
    const float* __restrict__ a14m, const float* __restrict__ W_pos,
    const float* __restrict__ b_pos, const ushort* __restrict__ Wt,
    const float* __restrict__ gamma, const float* __restrict__ beta,
    const int* __restrict__ R_idx, const int* __restrict__ chain,
    const float* __restrict__ idxf, float* __restrict__ E)
{
    __shared__ __align__(16) char arena[76160];
    ushort* Bs0   = (ushort*)arena;                  // 16384 B
    ushort* Bs1   = (ushort*)(arena + 16384);        // 16384 B
    __half* ddc   = (__half*)(arena + 32768);        // [96][200] fp16  38400 B
    ushort* eposs = (ushort*)(arena + 71168);        // [96][16] bf16    3072 B
    int*    jl    = (int*)(arena + 74240);           // [96]              384 B
    float*  lnS   = (float*)(arena + 74624);         // [96][2]           768 B
    float*  lnQ   = (float*)(arena + 75392);         // [96][2]           768 B
    // transient (inside Bs1 region, consumed before first Bs1 staging):
    __half* xjs = (__half*)(arena + 16384);          // [96][48]         9216 B
    float*  mjs = (float*)(arena + 16384 + 9216);    // [96][16]         6144 B
    float*  xi  = (float*)(arena + 16384 + 15360);   // [3][44]           528 B
    float*  mi  = (float*)(arena + 16384 + 15888);   // [3][16]           192 B

    const int i0 = blockIdx.x * 3;
    const int tid = threadIdx.x;
    const int wave = tid >> 6, lane = tid & 63;

    // ---- A) neighbor index list ----
    if (tid < 96) {
        int g = tid >> 5, e = tid & 31;
        jl[tid] = (e < TOPK) ? (int)idxf[(i0 + g) * TOPK + e] : 0;
    }
    __syncthreads();

    // ---- B) stage transient geometry + E_pos ----
    for (int t = tid; t < 96 * 42; t += 256) {
        int row = t / 42, c = t - row * 42;
        xjs[row * 48 + c] = __float2half(x[jl[row] * 42 + c]);
    }
    for (int t = tid; t < 96 * 14; t += 256) {
        int row = t / 14, a = t - row * 14;
        int e = row & 31, j = jl[row];
        mjs[row * 16 + a] = (e < TOPK) ? a14m[j * 14 + a] * mask[j] : 0.f;
    }
    if (tid < 126) {
        int g = tid / 42, c = tid - g * 42;
        xi[g * 44 + c] = x[(i0 + g) * 42 + c];
    } else if (tid < 126 + 42) {
        int t = tid - 126; int g = t / 14, a = t - g * 14;
        mi[g * 16 + a] = a14m[(i0 + g) * 14 + a] * mask[i0 + g];
    }
    for (int t = tid; t < 96 * 16; t += 256) {
        int row = t >> 4, c = t & 15;
        int e = row & 31, g = row >> 5;
        float v = 0.f;
        if (e < TOPK) {
            int i = i0 + g, j = jl[row];
            int off = R_idx[i] - R_idx[j];
            int ec = (chain[i] == chain[j]) ? 1 : 0;
            int dc = off + 32; dc = dc < 0 ? 0 : (dc > 64 ? 64 : dc);
            int d = ec ? dc : 65;
            v = W_pos[d * 16 + c] + b_pos[c];
        }
        eposs[row * 16 + c] = f2bf(v);
    }
    __syncthreads();

    // ---- C) issue Bs0 staging (chunk 0), then compute ddc ----
    const int srow = wave * 32 + (lane >> 3);
    const int sseg = (lane & 7) ^ ((lane >> 3) & 7);
    const ushort* gsrc = Wt + (size_t)srow * KPAD + sseg * 8;
    #pragma unroll
    for (int it = 0; it < 4; ++it)
        ASYNC16(Bs0 + wave * 2048 + it * 512, gsrc + (size_t)it * 8 * KPAD);

    for (int t = tid; t < 96 * 196; t += 256) {
        int row = t / 196, p = t - row * 196;
        int a1 = p / 14, a2 = p - a1 * 14;
        int g = row >> 5;
        float dx = xi[g * 44 + a1 * 3 + 0] - __half2float(xjs[row * 48 + a2 * 3 + 0]);
        float dy = xi[g * 44 + a1 * 3 + 1] - __half2float(xjs[row * 48 + a2 * 3 + 1]);
        float dz = xi[g * 44 + a1 * 3 + 2] - __half2float(xjs[row * 48 + a2 * 3 + 2]);
        float dd = sqrtf(dx * dx + dy * dy + dz * dz + 1e-6f);
        float coef = mi[g * 16 + a1] * mjs[row * 16 + a2];
        float de = (coef > 0.5f) ? fminf(dd, 40.f) : 40.f;  // 40 -> exact zero row
        ddc[row * 200 + p] = __float2half(de);
    }
    __syncthreads();   // drains vmcnt (Bs0) + lgkm (ddc)

    // ---- main loop setup ----
    const int l16 = lane & 15, lk = lane >> 4;
    const int mh = wave >> 1, nh = wave & 1;
    const int r0 = 8 * (lk & 1);
    const float mu0 = (float)r0 * 1.33333333f;
    float wc[7];
    #pragma unroll
    for (int j = 1; j < 8; ++j)
        wc[j - 1] = __expf(-1.13777778f * (float)(2 * (r0 + j) - 1));

    int boff[2][4];
    #pragma unroll
    for (int ks = 0; ks < 2; ++ks)
        #pragma unroll
        for (int nf = 0; nf < 4; ++nf) {
            int n = nh * 64 + nf * 16 + l16;
            boff[ks][nf] = n * 64 + ((((ks << 2) | lk) ^ (n & 7)) << 3);
        }
    int doff[3], eoff[3];
    #pragma unroll
    for (int mf = 0; mf < 3; ++mf) {
        int row = mh * 48 + mf * 16 + l16;
        doff[mf] = row * 200;
        eoff[mf] = row * 16 + r0;
    }

    f32x4 acc[3][4] = {};

    for (int ch = 0; ch < NCHUNK; ++ch) {
        ushort* Bq = (ch & 1) ? Bs1 : Bs0;
        ushort* Bn = (ch & 1) ? Bs0 : Bs1;
        // 1. stage next chunk (async; lands before next iter's barrier)
        if (ch + 1 < NCHUNK) {
            #pragma unroll
            for (int it = 0; it < 4; ++it)
                ASYNC16(Bn + wave * 2048 + it * 512,
                        gsrc + (size_t)it * 8 * KPAD + (ch + 1) * 64);
        }
        // 2. B fragments from LDS (swizzled, conflict-free)
        bf16x8 bf[2][4];
        #pragma unroll
        for (int ks = 0; ks < 2; ++ks)
            #pragma unroll
            for (int nf = 0; nf < 4; ++nf)
                bf[ks][nf] = *(const bf16x8*)&Bq[boff[ks][nf]];
        // 3. A fragments built in registers (chain-of-8 exp recurrence)
        bf16x8 af[2][3];
        #pragma unroll
        for (int ks = 0; ks < 2; ++ks) {
            const int p = 4 * ch + 2 * ks + (lk >> 1) - 1;
            #pragma unroll
            for (int mf = 0; mf < 3; ++mf) {
                if (p < 0) {
                    af[ks][mf] = *(const bf16x8*)&eposs[eoff[mf]];
                } else if (p < 196) {
                    float dd = __half2float(ddc[doff[mf] + p]);
                    float w = __expf(1.70666667f * dd);
                    float t0 = (dd - mu0) * 0.8f;
                    float ev[8];
                    ev[0] = __expf(-t0 * t0);
                    #pragma unroll
                    for (int j = 1; j < 8; ++j) ev[j] = ev[j - 1] * w * wc[j - 1];
                    union { ushort u[8]; bf16x8 v; } o;
                    #pragma unroll
                    for (int j = 0; j < 8; ++j) o.u[j] = f2bf(ev[j]);
                    af[ks][mf] = o.v;
                } else {
                    af[ks][mf] = (bf16x8){0, 0, 0, 0, 0, 0, 0, 0};
                }
            }
        }
        // 4. MFMA
        #pragma unroll
        for (int ks = 0; ks < 2; ++ks)
            #pragma unroll
            for (int mf = 0; mf < 3; ++mf)
                #pragma unroll
                for (int nf = 0; nf < 4; ++nf)
                    acc[mf][nf] = __builtin_amdgcn_mfma_f32_16x16x32_bf16(
                        af[ks][mf], bf[ks][nf], acc[mf][nf], 0, 0, 0);
        // 5. single barrier (drains vmcnt for staged loads + syncs buffers)
        __syncthreads();
    }

    // ---- LayerNorm epilogue (C/D: col = lane&15, row = lk*4+reg) ----
    #pragma unroll
    for (int mf = 0; mf < 3; ++mf)
        #pragma unroll
        for (int reg = 0; reg < 4; ++reg) {
            float s = acc[mf][0][reg] + acc[mf][1][reg] + acc[mf][2][reg] + acc[mf][3][reg];
            float q = acc[mf][0][reg] * acc[mf][0][reg] + acc[mf][1][reg] * acc[mf][1][reg]
                    + acc[mf][2][reg] * acc[mf][2][reg] + acc[mf][3][reg] * acc[mf][3][reg];
            #pragma unroll
            for (int m = 1; m < 16; m <<= 1) {
                s += __shfl_xor(s, m);
                q += __shfl_xor(q, m);
            }
            if (l16 == 0) {
                int row = mh * 48 + mf * 16 + lk * 4 + reg;
                lnS[row * 2 + nh] = s;
                lnQ[row * 2 + nh] = q;
            }
        }
    __syncthreads();

    float gl[4], bl[4];
    #pragma unroll
    for (int nf = 0; nf < 4; ++nf) {
        int col = nh * 64 + nf * 16 + l16;
        gl[nf] = gamma[col];
        bl[nf] = beta[col];
    }
    #pragma unroll
    for (int mf = 0; mf < 3; ++mf)
        #pragma unroll
        for (int reg = 0; reg < 4; ++reg) {
            int r = mh * 48 + mf * 16 + lk * 4 + reg;
            int e = r & 31, g = r >> 5;
            if (e < TOPK) {
                float s = lnS[r * 2 + 0] + lnS[r * 2 + 1];
                float q = lnQ[r * 2 + 0] + lnQ[r * 2 + 1];
                float mean = s * (1.f / 128.f);
                float var = q * (1.f / 128.f) - mean * mean;
                float inv = 1.f / sqrtf(var + 1e-5f);
                float* dst = &E[((size_t)((i0 + g) * TOPK + e)) * 128];
                #pragma unroll
                for (int nf = 0; nf < 4; ++nf) {
                    int col = nh * 64 + nf * 16 + l16;
                    dst[col] = (acc[mf][nf][reg] - mean) * inv * gl[nf] + bl[nf];
                }
            }
        }
}

// ---------------------------------------------------------------------------
extern "C" void kernel_launch(void* const* d_in, const int* in_sizes, int n_in,
                              void* d_out, int out_size, void* d_ws, size_t ws_size,
                              hipStream_t stream)
{
    const float* x       = (const float*)d_in[0];
    const float* mask    = (const float*)d_in[1];
    const float* a14m    = (const float*)d_in[2];
    const float* feat    = (const float*)d_in[3];
    const float* W_pos   = (const float*)d_in[4];
    const float* b_pos   = (const float*)d_in[5];
    const float* W_edge  = (const float*)d_in[6];
    const float* gamma_e = (const float*)d_in[7];
    const float* beta_e  = (const float*)d_in[8];
    const float* W_node  = (const float*)d_in[9];
    const float* gamma_n = (const float*)d_in[10];
    const float* beta_n  = (const float*)d_in[11];
    const int*   S       = (const int*)d_in[12];
    const int*   R_idx   = (const int*)d_in[13];
    const int*   chain   = (const int*)d_in[14];

    float* out     = (float*)d_out;
    float* V       = out;                                  // 1536*128
    float* E       = out + 196608;                         // 1536*30*128
    float* out_idx = out + 196608 + 5898240;               // 1536*30
    float* out_x   = out_idx + 46080;                      // 1536*14*3

    ushort* Wt = (ushort*)d_ws;                            // 128*3200 bf16

    prep_kernel<<<PREP_BLKS, 256, 0, stream>>>(
        x, mask, feat, W_edge, Wt, W_node, gamma_n, beta_n, S, V, out_idx, out_x);
    edge_mfma_kernel<<<EDGE_BLKS, 256, 0, stream>>>(
        x, mask, a14m, W_pos, b_pos, Wt, gamma_e, beta_e, R_idx, chain,
        out_idx, E);
}

// Round 6
// 122.215 us; speedup vs baseline: 1.0716x; 1.0716x over previous
//
#include <hip/hip_runtime.h>
#include <hip/hip_bf16.h>
#include <hip/hip_fp16.h>
#include <math.h>

#define LL 1536
#define NA 14
#define TOPK 30
#define KDIM 3152          // 16 (pos) + 14*14*16 (rbf)
#define KPAD 3200
#define NCHUNK 50          // K chunks of 64

#define TOPK_BLKS 384      // 4 rows per block
#define CONV_BLKS 100
#define NODE_BLKS 384      // 4 rows per block
#define PREP_BLKS (TOPK_BLKS + CONV_BLKS + NODE_BLKS)

#define EDGE_BLKS 768      // 2 residues per block (M = 64 rows); 3 blocks/CU

typedef __attribute__((ext_vector_type(8))) short bf16x8;
typedef __attribute__((ext_vector_type(4))) float f32x4;

static __device__ __forceinline__ ushort f2bf(float f) {
    union { __hip_bfloat16 h; ushort u; } v;
    v.h = __float2bfloat16(f);
    return v.u;
}

// fast exp2 (raw v_exp_f32)
static __device__ __forceinline__ float fexp2(float f) {
    return __builtin_amdgcn_exp2f(f);
}

// packed RNE f32x2 -> bf16x2 (1 instruction; no builtin on gfx950)
static __device__ __forceinline__ unsigned cvt_pk_bf16(float lo, float hi) {
    unsigned r;
    asm("v_cvt_pk_bf16_f32 %0, %1, %2" : "=v"(r) : "v"(lo), "v"(hi));
    return r;
}

static __device__ __forceinline__ unsigned long long u64min(
    unsigned long long a, unsigned long long b) { return a < b ? a : b; }

#define ASYNC16(ldsp, gp)                                                     \
    __builtin_amdgcn_global_load_lds(                                         \
        (const __attribute__((address_space(1))) void*)(gp),                  \
        (__attribute__((address_space(3))) void*)(ldsp), 16, 0, 0)

// ---------------------------------------------------------------------------
// prep kernel: fuses top-k (+x passthrough), W_edge transpose/convert, node LN
// ---------------------------------------------------------------------------
__global__ __launch_bounds__(256) void prep_kernel(
    const float* __restrict__ x, const float* __restrict__ mask,
    const float* __restrict__ feat,
    const float* __restrict__ W_edge, ushort* __restrict__ Wt,
    const float* __restrict__ W_node, const float* __restrict__ gamma_n,
    const float* __restrict__ beta_n, const int* __restrict__ S,
    float* __restrict__ V, float* __restrict__ out_idx, float* __restrict__ out_x)
{
    __shared__ __align__(16) char sm[24576];
    const int blk = blockIdx.x;
    const int tid = threadIdx.x;

    if (blk < TOPK_BLKS) {
        // ---------------- top-30 (4 rows per block, 1 row per wave) --------
        float* ca  = (float*)sm;            // [1536*3]
        float* msk = (float*)sm + 4608;     // [1536]
        for (int t = tid; t < LL; t += 256) {
            msk[t] = mask[t];
            ca[t * 3 + 0] = x[t * 42 + 3];
            ca[t * 3 + 1] = x[t * 42 + 4];
            ca[t * 3 + 2] = x[t * 42 + 5];
        }
        __syncthreads();

        const int lane = tid & 63;
        const int i = blk * 4 + (tid >> 6);
        const float cix = ca[i * 3 + 0], ciy = ca[i * 3 + 1], ciz = ca[i * 3 + 2];
        const float mi = msk[i];

        float d[24], m2a[24];
        float lmax = 0.f;
        #pragma unroll
        for (int c = 0; c < 24; ++c) {
            int j = lane + c * 64;
            float dx = ca[j * 3 + 0] - cix;
            float dy = ca[j * 3 + 1] - ciy;
            float dz = ca[j * 3 + 2] - ciz;
            float m2 = mi * msk[j];
            float D = m2 * sqrtf(dx * dx + dy * dy + dz * dz + 1e-6f);
            d[c] = D; m2a[c] = m2;
            lmax = fmaxf(lmax, D);
        }
        #pragma unroll
        for (int m = 1; m < 64; m <<= 1) lmax = fmaxf(lmax, __shfl_xor(lmax, m));

        unsigned long long key[24];
        #pragma unroll
        for (int c = 0; c < 24; ++c) {
            float adj = d[c] + (1.f - m2a[c]) * lmax;
            key[c] = ((unsigned long long)__float_as_uint(adj) << 32)
                   | (unsigned)(lane + c * 64);
        }
        for (int t = 0; t < TOPK; ++t) {
            unsigned long long m12[12];
            #pragma unroll
            for (int c = 0; c < 12; ++c) m12[c] = u64min(key[2 * c], key[2 * c + 1]);
            #pragma unroll
            for (int c = 0; c < 6; ++c) m12[c] = u64min(m12[2 * c], m12[2 * c + 1]);
            unsigned long long best = u64min(u64min(m12[0], m12[1]),
                u64min(m12[2], u64min(m12[3], u64min(m12[4], m12[5]))));
            #pragma unroll
            for (int m = 1; m < 64; m <<= 1) best = u64min(best, __shfl_xor(best, m));
            if (lane == 0) out_idx[i * TOPK + t] = (float)(unsigned)(best & 0xffffffffu);
            #pragma unroll
            for (int c = 0; c < 24; ++c) if (key[c] == best) key[c] = ~0ull;
        }
        for (int t = lane; t < 42; t += 64) out_x[i * 42 + t] = x[i * 42 + t];

    } else if (blk < TOPK_BLKS + CONV_BLKS) {
        // ---------------- W_edge -> Wt bf16 transpose ----------------------
        int cb = blk - TOPK_BLKS;
        int k0 = (cb % 50) * 64, n0 = (cb / 50) * 64;
        float (*tile)[65] = (float (*)[65])sm;
        #pragma unroll
        for (int r = 0; r < 16; ++r) {
            int idx = r * 256 + tid;
            int kl = idx >> 6, nl = idx & 63;
            int k = k0 + kl;
            tile[nl][kl] = (k < KDIM) ? W_edge[k * 128 + n0 + nl] : 0.f;
        }
        __syncthreads();
        #pragma unroll
        for (int r = 0; r < 8; ++r) {          // pairs along k, packed u32 store
            int idx = r * 256 + tid;
            int nl = idx >> 5, kp = (idx & 31) * 2;
            unsigned pk = cvt_pk_bf16(tile[nl][kp], tile[nl][kp + 1]);
            *(unsigned*)&Wt[(size_t)(n0 + nl) * KPAD + k0 + kp] = pk;
        }

    } else {
        // ---------------- node features (1 row per wave) -------------------
        int nb = blk - TOPK_BLKS - CONV_BLKS;
        float* f = (float*)sm;                     // [4][128]
        const int w = tid >> 6, lane = tid & 63;
        const int i = nb * 4 + w;
        f[w * 128 + lane] = feat[i * 128 + lane];
        f[w * 128 + 64 + lane] = feat[i * 128 + 64 + lane];
        __syncthreads();
        int s = S[i];
        float a0 = W_node[s * 128 + lane];
        float a1 = W_node[s * 128 + 64 + lane];
        #pragma unroll 8
        for (int c = 0; c < 128; ++c) {
            float fc = f[w * 128 + c];
            a0 = fmaf(fc, W_node[(21 + c) * 128 + lane], a0);
            a1 = fmaf(fc, W_node[(21 + c) * 128 + 64 + lane], a1);
        }
        float ss = a0 + a1, qq = a0 * a0 + a1 * a1;
        #pragma unroll
        for (int m = 1; m < 64; m <<= 1) {
            ss += __shfl_xor(ss, m);
            qq += __shfl_xor(qq, m);
        }
        float mean = ss * (1.f / 128.f);
        float var = qq * (1.f / 128.f) - mean * mean;
        float inv = 1.f / sqrtf(var + 1e-5f);
        V[i * 128 + lane]      = (a0 - mean) * inv * gamma_n[lane] + beta_n[lane];
        V[i * 128 + 64 + lane] = (a1 - mean) * inv * gamma_n[64 + lane] + beta_n[64 + lane];
    }
}

// ---------------------------------------------------------------------------
// edge kernel: block = 2 residues (M=64 rows), C[64x128] = A[64x3200] @ Wt^T.
// A-fragments built in registers (cvt_pk packing, exp2-form exponentials);
// dd precomputed fp16 in LDS (masks folded); Bs double-buffered via
// global_load_lds with pre-swizzled source; 1 barrier per K-chunk.
// Waves: 2x2 grid of 32x64 tiles. ~45 KB LDS -> 3 blocks/CU.
// ---------------------------------------------------------------------------
__global__ __launch_bounds__(256, 3) void edge_mfma_kernel(
    const float* __restrict__ x, const float* __restrict__ mask,
    const float* __restrict__ a14m, const float* __restrict__ W_pos,
    const float* __restrict__ b_pos, const ushort* __restrict__ Wt,
    const float* __restrict__ gamma, const float* __restrict__ beta,
    const int* __restrict__ R_idx, const int* __restrict__ chain,
    const float* __restrict__ idxf, float* __restrict__ E)
{
    __shared__ __align__(16) char arena[45312];
    ushort* Bs0   = (ushort*)arena;                  // 8192 B
    ushort* Bs1   = (ushort*)(arena + 8192);         // 8192 B
    __half* ddc   = (__half*)(arena + 16384);        // [64][200] fp16  25600 B
    ushort* eposs = (ushort*)(arena + 41984);        // [64][16] bf16    2048 B
    int*    jl    = (int*)(arena + 44032);           // [64]              256 B
    float*  lnS   = (float*)(arena + 44288);         // [64][2]           512 B
    float*  lnQ   = (float*)(arena + 44800);         // [64][2]           512 B
    // transient (inside ddc region, consumed before ddc written):
    __half* xjs = (__half*)(arena + 16384);          // [64][48]         6144 B
    float*  mjs = (float*)(arena + 16384 + 6144);    // [64][16]         4096 B
    float*  xi  = (float*)(arena + 16384 + 10240);   // [2][44]           352 B
    float*  mi  = (float*)(arena + 16384 + 10624);   // [2][16]           128 B

    const int i0 = blockIdx.x * 2;
    const int tid = threadIdx.x;
    const int wave = tid >> 6, lane = tid & 63;

    // ---- A) neighbor index list ----
    if (tid < 64) {
        int g = tid >> 5, e = tid & 31;
        jl[tid] = (e < TOPK) ? (int)idxf[(i0 + g) * TOPK + e] : 0;
    }
    __syncthreads();

    // ---- B) stage transient geometry + E_pos ----
    for (int t = tid; t < 64 * 42; t += 256) {
        int row = t / 42, c = t - row * 42;
        xjs[row * 48 + c] = __float2half(x[jl[row] * 42 + c]);
    }
    for (int t = tid; t < 64 * 14; t += 256) {
        int row = t / 14, a = t - row * 14;
        int e = row & 31, j = jl[row];
        mjs[row * 16 + a] = (e < TOPK) ? a14m[j * 14 + a] * mask[j] : 0.f;
    }
    if (tid < 84) {
        int g = tid / 42, c = tid - g * 42;
        xi[g * 44 + c] = x[(i0 + g) * 42 + c];
    } else if (tid < 84 + 28) {
        int t = tid - 84; int g = t / 14, a = t - g * 14;
        mi[g * 16 + a] = a14m[(i0 + g) * 14 + a] * mask[i0 + g];
    }
    for (int t = tid; t < 64 * 16; t += 256) {
        int row = t >> 4, c = t & 15;
        int e = row & 31, g = row >> 5;
        float v = 0.f;
        if (e < TOPK) {
            int i = i0 + g, j = jl[row];
            int off = R_idx[i] - R_idx[j];
            int ec = (chain[i] == chain[j]) ? 1 : 0;
            int dc = off + 32; dc = dc < 0 ? 0 : (dc > 64 ? 64 : dc);
            int d = ec ? dc : 65;
            v = W_pos[d * 16 + c] + b_pos[c];
        }
        eposs[row * 16 + c] = f2bf(v);
    }
    __syncthreads();

    // ---- C) issue Bs0 staging (chunk 0) ----
    const int srow = wave * 32 + (lane >> 3);
    const int sseg = (lane & 7) ^ ((lane >> 3) & 7);
    const ushort* gsrc = Wt + (size_t)srow * KPAD + sseg * 8;
    #pragma unroll
    for (int it = 0; it < 4; ++it)
        ASYNC16(Bs0 + wave * 2048 + it * 512, gsrc + (size_t)it * 8 * KPAD);

    // ---- D) dd table (fp16, masks folded: masked -> 40 => exact zero row).
    // ddc overlays the transient inputs, so: compute all values into
    // registers (2 passes x 25), barrier, then write.
    {
        float vals[25];
        int cnt = 0;
        for (int t = tid; t < 64 * 196; t += 512) {
            int row = t / 196, p = t - row * 196;
            int a1 = p / 14, a2 = p - a1 * 14;
            int g = row >> 5;
            float dx = xi[g * 44 + a1 * 3 + 0] - __half2float(xjs[row * 48 + a2 * 3 + 0]);
            float dy = xi[g * 44 + a1 * 3 + 1] - __half2float(xjs[row * 48 + a2 * 3 + 1]);
            float dz = xi[g * 44 + a1 * 3 + 2] - __half2float(xjs[row * 48 + a2 * 3 + 2]);
            float dd = sqrtf(dx * dx + dy * dy + dz * dz + 1e-6f);
            float coef = mi[g * 16 + a1] * mjs[row * 16 + a2];
            vals[cnt++] = (coef > 0.5f) ? fminf(dd, 27.f) : 40.f;
        }
        float vals2[25];
        int cnt2 = 0;
        for (int t = tid + 256; t < 64 * 196; t += 512) {
            int row = t / 196, p = t - row * 196;
            int a1 = p / 14, a2 = p - a1 * 14;
            int g = row >> 5;
            float dx = xi[g * 44 + a1 * 3 + 0] - __half2float(xjs[row * 48 + a2 * 3 + 0]);
            float dy = xi[g * 44 + a1 * 3 + 1] - __half2float(xjs[row * 48 + a2 * 3 + 1]);
            float dz = xi[g * 44 + a1 * 3 + 2] - __half2float(xjs[row * 48 + a2 * 3 + 2]);
            float dd = sqrtf(dx * dx + dy * dy + dz * dz + 1e-6f);
            float coef = mi[g * 16 + a1] * mjs[row * 16 + a2];
            vals2[cnt2++] = (coef > 0.5f) ? fminf(dd, 27.f) : 40.f;
        }
        __syncthreads();   // all reads of transients done
        cnt = 0;
        for (int t = tid; t < 64 * 196; t += 512) {
            int row = t / 196, p = t - row * 196;
            ddc[row * 200 + p] = __float2half(vals[cnt++]);
        }
        cnt2 = 0;
        for (int t = tid + 256; t < 64 * 196; t += 512) {
            int row = t / 196, p = t - row * 196;
            ddc[row * 200 + p] = __float2half(vals2[cnt2++]);
        }
    }
    __syncthreads();   // ddc ready; Bs0 staging also drained here

    // ---- main loop setup ----
    const int l16 = lane & 15, lk = lane >> 4;
    const int mh = wave >> 1, nh = wave & 1;
    const int r0 = 8 * (lk & 1);
    const float mu0 = (float)r0 * 1.33333333f;
    float wc[7];
    #pragma unroll
    for (int j = 1; j < 8; ++j)
        wc[j - 1] = __expf(-1.13777778f * (float)(2 * (r0 + j) - 1));

    int boff[2][4];
    #pragma unroll
    for (int ks = 0; ks < 2; ++ks)
        #pragma unroll
        for (int nf = 0; nf < 4; ++nf) {
            int n = nh * 64 + nf * 16 + l16;
            boff[ks][nf] = n * 64 + ((((ks << 2) | lk) ^ (n & 7)) << 3);
        }
    int doff[2], eoff[2];
    #pragma unroll
    for (int mf = 0; mf < 2; ++mf) {
        int row = mh * 32 + mf * 16 + l16;
        doff[mf] = row * 200;
        eoff[mf] = row * 16 + r0;
    }

    f32x4 acc[2][4] = {};

    for (int ch = 0; ch < NCHUNK; ++ch) {
        ushort* Bq = (ch & 1) ? Bs1 : Bs0;
        ushort* Bn = (ch & 1) ? Bs0 : Bs1;
        // 1. stage next chunk (async; drained by end-of-iter barrier)
        if (ch + 1 < NCHUNK) {
            #pragma unroll
            for (int it = 0; it < 4; ++it)
                ASYNC16(Bn + wave * 2048 + it * 512,
                        gsrc + (size_t)it * 8 * KPAD + (ch + 1) * 64);
        }
        // 2. B fragments from LDS (swizzled, conflict-light)
        bf16x8 bfr[2][4];
        #pragma unroll
        for (int ks = 0; ks < 2; ++ks)
            #pragma unroll
            for (int nf = 0; nf < 4; ++nf)
                bfr[ks][nf] = *(const bf16x8*)&Bq[boff[ks][nf]];
        // 3. A fragments in registers (exp2-form chain, cvt_pk packing)
        bf16x8 af[2][2];
        #pragma unroll
        for (int ks = 0; ks < 2; ++ks) {
            const int p = 4 * ch + 2 * ks + (lk >> 1) - 1;
            #pragma unroll
            for (int mf = 0; mf < 2; ++mf) {
                if (p < 0) {
                    af[ks][mf] = *(const bf16x8*)&eposs[eoff[mf]];
                } else if (p < 196) {
                    float dd = __half2float(ddc[doff[mf] + p]);
                    float w = fexp2(dd * 2.46219921f);        // exp(1.70667*dd)
                    float s = dd - mu0;
                    float ev[8];
                    ev[0] = fexp2(s * s * -0.92332483f);      // exp(-(0.8 s)^2)
                    #pragma unroll
                    for (int j = 1; j < 8; ++j) ev[j] = ev[j - 1] * w * wc[j - 1];
                    union { unsigned u[4]; bf16x8 v; } o;
                    #pragma unroll
                    for (int j = 0; j < 4; ++j)
                        o.u[j] = cvt_pk_bf16(ev[2 * j], ev[2 * j + 1]);
                    af[ks][mf] = o.v;
                } else {
                    af[ks][mf] = (bf16x8){0, 0, 0, 0, 0, 0, 0, 0};
                }
            }
        }
        // 4. MFMA
        #pragma unroll
        for (int ks = 0; ks < 2; ++ks)
            #pragma unroll
            for (int mf = 0; mf < 2; ++mf)
                #pragma unroll
                for (int nf = 0; nf < 4; ++nf)
                    acc[mf][nf] = __builtin_amdgcn_mfma_f32_16x16x32_bf16(
                        af[ks][mf], bfr[ks][nf], acc[mf][nf], 0, 0, 0);
        // 5. single barrier per chunk (drains staged loads, syncs buffers)
        __syncthreads();
    }

    // ---- LayerNorm epilogue (C/D: col = lane&15, row = (lane>>4)*4+reg) ----
    #pragma unroll
    for (int mf = 0; mf < 2; ++mf)
        #pragma unroll
        for (int reg = 0; reg < 4; ++reg) {
            float s = acc[mf][0][reg] + acc[mf][1][reg] + acc[mf][2][reg] + acc[mf][3][reg];
            float q = acc[mf][0][reg] * acc[mf][0][reg] + acc[mf][1][reg] * acc[mf][1][reg]
                    + acc[mf][2][reg] * acc[mf][2][reg] + acc[mf][3][reg] * acc[mf][3][reg];
            #pragma unroll
            for (int m = 1; m < 16; m <<= 1) {
                s += __shfl_xor(s, m);
                q += __shfl_xor(q, m);
            }
            if (l16 == 0) {
                int row = mh * 32 + mf * 16 + lk * 4 + reg;
                lnS[row * 2 + nh] = s;
                lnQ[row * 2 + nh] = q;
            }
        }
    __syncthreads();

    float gl[4], bl[4];
    #pragma unroll
    for (int nf = 0; nf < 4; ++nf) {
        int col = nh * 64 + nf * 16 + l16;
        gl[nf] = gamma[col];
        bl[nf] = beta[col];
    }
    #pragma unroll
    for (int mf = 0; mf < 2; ++mf)
        #pragma unroll
        for (int reg = 0; reg < 4; ++reg) {
            int r = mh * 32 + mf * 16 + lk * 4 + reg;
            int e = r & 31, g = r >> 5;
            if (e < TOPK) {
                float s = lnS[r * 2 + 0] + lnS[r * 2 + 1];
                float q = lnQ[r * 2 + 0] + lnQ[r * 2 + 1];
                float mean = s * (1.f / 128.f);
                float var = q * (1.f / 128.f) - mean * mean;
                float inv = 1.f / sqrtf(var + 1e-5f);
                float* dst = &E[((size_t)((i0 + g) * TOPK + e)) * 128];
                #pragma unroll
                for (int nf = 0; nf < 4; ++nf) {
                    int col = nh * 64 + nf * 16 + l16;
                    dst[col] = (acc[mf][nf][reg] - mean) * inv * gl[nf] + bl[nf];
                }
            }
        }
}

// ---------------------------------------------------------------------------
extern "C" void kernel_launch(void* const* d_in, const int* in_sizes, int n_in,
                              void* d_out, int out_size, void* d_ws, size_t ws_size,
                              hipStream_t stream)
{
    const float* x       = (const float*)d_in[0];
    const float* mask    = (const float*)d_in[1];
    const float* a14m    = (const float*)d_in[2];
    const float* feat    = (const float*)d_in[3];
    const float* W_pos   = (const float*)d_in[4];
    const float* b_pos   = (const float*)d_in[5];
    const float* W_edge  = (const float*)d_in[6];
    const float* gamma_e = (const float*)d_in[7];
    const float* beta_e  = (const float*)d_in[8];
    const float* W_node  = (const float*)d_in[9];
    const float* gamma_n = (const float*)d_in[10];
    const float* beta_n  = (const float*)d_in[11];
    const int*   S       = (const int*)d_in[12];
    const int*   R_idx   = (const int*)d_in[13];
    const int*   chain   = (const int*)d_in[14];

    float* out     = (float*)d_out;
    float* V       = out;                                  // 1536*128
    float* E       = out + 196608;                         // 1536*30*128
    float* out_idx = out + 196608 + 5898240;               // 1536*30
    float* out_x   = out_idx + 46080;                      // 1536*14*3

    ushort* Wt = (ushort*)d_ws;                            // 128*3200 bf16

    prep_kernel<<<PREP_BLKS, 256, 0, stream>>>(
        x, mask, feat, W_edge, Wt, W_node, gamma_n, beta_n, S, V, out_idx, out_x);
    edge_mfma_kernel<<<EDGE_BLKS, 256, 0, stream>>>(
        x, mask, a14m, W_pos, b_pos, Wt, gamma_e, beta_e, R_idx, chain,
        out_idx, E);
}

// Round 7
// 121.337 us; speedup vs baseline: 1.0793x; 1.0072x over previous
//
#include <hip/hip_runtime.h>
#include <hip/hip_bf16.h>
#include <hip/hip_fp16.h>
#include <math.h>

#define LL 1536
#define NA 14
#define TOPK 30
#define KDIM 3152          // 16 (pos) + 14*14*16 (rbf)
#define KPAD 3200
#define NCHUNK 50          // K chunks of 64

#define TOPK_BLKS 384      // 4 rows per block
#define CONV_BLKS 100
#define NODE_BLKS 384      // 4 rows per block
#define PREP_BLKS (TOPK_BLKS + CONV_BLKS + NODE_BLKS)

#define EDGE_BLKS 768      // 2 residues per block (M = 64 rows); 3 blocks/CU

typedef __attribute__((ext_vector_type(8))) short bf16x8;
typedef __attribute__((ext_vector_type(4))) float f32x4;

static __device__ __forceinline__ ushort f2bf(float f) {
    union { __hip_bfloat16 h; ushort u; } v;
    v.h = __float2bfloat16(f);
    return v.u;
}

// fast exp2 (raw v_exp_f32)
static __device__ __forceinline__ float fexp2(float f) {
    return __builtin_amdgcn_exp2f(f);
}

// packed RNE f32x2 -> bf16x2 (1 instruction; no builtin on gfx950)
static __device__ __forceinline__ unsigned cvt_pk_bf16(float lo, float hi) {
    unsigned r;
    asm("v_cvt_pk_bf16_f32 %0, %1, %2" : "=v"(r) : "v"(lo), "v"(hi));
    return r;
}

static __device__ __forceinline__ unsigned long long u64min(
    unsigned long long a, unsigned long long b) { return a < b ? a : b; }

#define ASYNC16(ldsp, gp)                                                     \
    __builtin_amdgcn_global_load_lds(                                         \
        (const __attribute__((address_space(1))) void*)(gp),                  \
        (__attribute__((address_space(3))) void*)(ldsp), 16, 0, 0)

// ---------------------------------------------------------------------------
// prep kernel: fuses top-k (+x passthrough), W_edge transpose/convert, node LN
// ---------------------------------------------------------------------------
__global__ __launch_bounds__(256) void prep_kernel(
    const float* __restrict__ x, const float* __restrict__ mask,
    const float* __restrict__ feat,
    const float* __restrict__ W_edge, ushort* __restrict__ Wt,
    const float* __restrict__ W_node, const float* __restrict__ gamma_n,
    const float* __restrict__ beta_n, const int* __restrict__ S,
    float* __restrict__ V, float* __restrict__ out_idx, float* __restrict__ out_x)
{
    __shared__ __align__(16) char sm[24576];
    const int blk = blockIdx.x;
    const int tid = threadIdx.x;

    if (blk < TOPK_BLKS) {
        // ---------------- top-30 (4 rows per block, 1 row per wave) --------
        float* ca  = (float*)sm;            // [1536*3]
        float* msk = (float*)sm + 4608;     // [1536]
        for (int t = tid; t < LL; t += 256) {
            msk[t] = mask[t];
            ca[t * 3 + 0] = x[t * 42 + 3];
            ca[t * 3 + 1] = x[t * 42 + 4];
            ca[t * 3 + 2] = x[t * 42 + 5];
        }
        __syncthreads();

        const int lane = tid & 63;
        const int i = blk * 4 + (tid >> 6);
        const float cix = ca[i * 3 + 0], ciy = ca[i * 3 + 1], ciz = ca[i * 3 + 2];
        const float mi = msk[i];

        float d[24], m2a[24];
        float lmax = 0.f;
        #pragma unroll
        for (int c = 0; c < 24; ++c) {
            int j = lane + c * 64;
            float dx = ca[j * 3 + 0] - cix;
            float dy = ca[j * 3 + 1] - ciy;
            float dz = ca[j * 3 + 2] - ciz;
            float m2 = mi * msk[j];
            float D = m2 * sqrtf(dx * dx + dy * dy + dz * dz + 1e-6f);
            d[c] = D; m2a[c] = m2;
            lmax = fmaxf(lmax, D);
        }
        #pragma unroll
        for (int m = 1; m < 64; m <<= 1) lmax = fmaxf(lmax, __shfl_xor(lmax, m));

        unsigned long long key[24];
        #pragma unroll
        for (int c = 0; c < 24; ++c) {
            float adj = d[c] + (1.f - m2a[c]) * lmax;
            key[c] = ((unsigned long long)__float_as_uint(adj) << 32)
                   | (unsigned)(lane + c * 64);
        }
        for (int t = 0; t < TOPK; ++t) {
            unsigned long long m12[12];
            #pragma unroll
            for (int c = 0; c < 12; ++c) m12[c] = u64min(key[2 * c], key[2 * c + 1]);
            #pragma unroll
            for (int c = 0; c < 6; ++c) m12[c] = u64min(m12[2 * c], m12[2 * c + 1]);
            unsigned long long best = u64min(u64min(m12[0], m12[1]),
                u64min(m12[2], u64min(m12[3], u64min(m12[4], m12[5]))));
            #pragma unroll
            for (int m = 1; m < 64; m <<= 1) best = u64min(best, __shfl_xor(best, m));
            if (lane == 0) out_idx[i * TOPK + t] = (float)(unsigned)(best & 0xffffffffu);
            #pragma unroll
            for (int c = 0; c < 24; ++c) if (key[c] == best) key[c] = ~0ull;
        }
        for (int t = lane; t < 42; t += 64) out_x[i * 42 + t] = x[i * 42 + t];

    } else if (blk < TOPK_BLKS + CONV_BLKS) {
        // ---------------- W_edge -> Wt bf16 transpose ----------------------
        int cb = blk - TOPK_BLKS;
        int k0 = (cb % 50) * 64, n0 = (cb / 50) * 64;
        float (*tile)[65] = (float (*)[65])sm;
        #pragma unroll
        for (int r = 0; r < 16; ++r) {
            int idx = r * 256 + tid;
            int kl = idx >> 6, nl = idx & 63;
            int k = k0 + kl;
            tile[nl][kl] = (k < KDIM) ? W_edge[k * 128 + n0 + nl] : 0.f;
        }
        __syncthreads();
        #pragma unroll
        for (int r = 0; r < 8; ++r) {          // pairs along k, packed u32 store
            int idx = r * 256 + tid;
            int nl = idx >> 5, kp = (idx & 31) * 2;
            unsigned pk = cvt_pk_bf16(tile[nl][kp], tile[nl][kp + 1]);
            *(unsigned*)&Wt[(size_t)(n0 + nl) * KPAD + k0 + kp] = pk;
        }

    } else {
        // ---------------- node features (1 row per wave) -------------------
        int nb = blk - TOPK_BLKS - CONV_BLKS;
        float* f = (float*)sm;                     // [4][128]
        const int w = tid >> 6, lane = tid & 63;
        const int i = nb * 4 + w;
        f[w * 128 + lane] = feat[i * 128 + lane];
        f[w * 128 + 64 + lane] = feat[i * 128 + 64 + lane];
        __syncthreads();
        int s = S[i];
        float a0 = W_node[s * 128 + lane];
        float a1 = W_node[s * 128 + 64 + lane];
        #pragma unroll 8
        for (int c = 0; c < 128; ++c) {
            float fc = f[w * 128 + c];
            a0 = fmaf(fc, W_node[(21 + c) * 128 + lane], a0);
            a1 = fmaf(fc, W_node[(21 + c) * 128 + 64 + lane], a1);
        }
        float ss = a0 + a1, qq = a0 * a0 + a1 * a1;
        #pragma unroll
        for (int m = 1; m < 64; m <<= 1) {
            ss += __shfl_xor(ss, m);
            qq += __shfl_xor(qq, m);
        }
        float mean = ss * (1.f / 128.f);
        float var = qq * (1.f / 128.f) - mean * mean;
        float inv = 1.f / sqrtf(var + 1e-5f);
        V[i * 128 + lane]      = (a0 - mean) * inv * gamma_n[lane] + beta_n[lane];
        V[i * 128 + 64 + lane] = (a1 - mean) * inv * gamma_n[64 + lane] + beta_n[64 + lane];
    }
}

// ---------------------------------------------------------------------------
// edge kernel: block = 2 residues (M=64 rows), C[64x128] = A[64x3200] @ Wt^T.
// Single 16KB Bs buffer (correct size!), race-free 2-barrier chunk loop.
// A-fragments built in registers; ddc (fp16 dd table, stride 200) lives in
// its OWN LDS region and is written directly -- inputs read from global
// (L1/L2-resident), so no overlay dance and no register-array spills.
// ~44.7 KB LDS -> 3 blocks/CU.
// ---------------------------------------------------------------------------
__global__ __launch_bounds__(256, 3) void edge_mfma_kernel(
    const float* __restrict__ x, const float* __restrict__ mask,
    const float* __restrict__ a14m, const float* __restrict__ W_pos,
    const float* __restrict__ b_pos, const ushort* __restrict__ Wt,
    const float* __restrict__ gamma, const float* __restrict__ beta,
    const int* __restrict__ R_idx, const int* __restrict__ chain,
    const float* __restrict__ idxf, float* __restrict__ E)
{
    __shared__ __align__(16) char arena[45824];
    ushort* Bs    = (ushort*)arena;                  // [128][64] bf16  16384 B
    __half* ddc   = (__half*)(arena + 16384);        // [64] stride 200 25600 B
    ushort* eposs = (ushort*)(arena + 41984);        // [64][16] bf16    2048 B
    int*    jl    = (int*)(arena + 44032);           // [64]              256 B
    float*  lnS   = (float*)(arena + 44288);         // [64][2]           512 B
    float*  lnQ   = (float*)(arena + 44800);         // [64][2]           512 B
    float*  xi    = (float*)(arena + 45312);         // [2][44]           352 B
    float*  mi    = (float*)(arena + 45664);         // [2][16]           128 B

    const int i0 = blockIdx.x * 2;
    const int tid = threadIdx.x;
    const int wave = tid >> 6, lane = tid & 63;

    // ---- A) neighbor index list + xi/mi ----
    if (tid < 64) {
        int g = tid >> 5, e = tid & 31;
        jl[tid] = (e < TOPK) ? (int)idxf[(i0 + g) * TOPK + e] : 0;
    } else if (tid < 64 + 84) {
        int t = tid - 64; int g = t / 42, c = t - g * 42;
        xi[g * 44 + c] = x[(i0 + g) * 42 + c];
    } else if (tid < 148 + 28) {
        int t = tid - 148; int g = t / 14, a = t - g * 14;
        mi[g * 16 + a] = a14m[(i0 + g) * 14 + a] * mask[i0 + g];
    }
    __syncthreads();

    // ---- B) issue Bs staging for chunk 0 (overlaps ddc pass) ----
    const int srow = wave * 32 + (lane >> 3);
    const int sseg = (lane & 7) ^ ((lane >> 3) & 7);
    const ushort* gsrc = Wt + (size_t)srow * KPAD + sseg * 8;
    #pragma unroll
    for (int it = 0; it < 4; ++it)
        ASYNC16(Bs + wave * 2048 + it * 512, gsrc + (size_t)it * 8 * KPAD);

    // ---- C) E_pos table ----
    for (int t = tid; t < 64 * 16; t += 256) {
        int row = t >> 4, c = t & 15;
        int e = row & 31, g = row >> 5;
        float v = 0.f;
        if (e < TOPK) {
            int i = i0 + g, j = jl[row];
            int off = R_idx[i] - R_idx[j];
            int ec = (chain[i] == chain[j]) ? 1 : 0;
            int dc = off + 32; dc = dc < 0 ? 0 : (dc > 64 ? 64 : dc);
            int d = ec ? dc : 65;
            v = W_pos[d * 16 + c] + b_pos[c];
        }
        eposs[row * 16 + c] = f2bf(v);
    }

    // ---- D) dd table: direct LDS writes, inputs from global (L1/L2) ----
    for (int t = tid; t < 64 * 196; t += 256) {
        int row = t / 196, p = t - row * 196;
        int a1 = p / 14, a2 = p - a1 * 14;
        int g = row >> 5, e = row & 31;
        int j = jl[row];
        const float* xj = &x[j * 42 + a2 * 3];
        float dx = xi[g * 44 + a1 * 3 + 0] - xj[0];
        float dy = xi[g * 44 + a1 * 3 + 1] - xj[1];
        float dz = xi[g * 44 + a1 * 3 + 2] - xj[2];
        float dd = sqrtf(dx * dx + dy * dy + dz * dz + 1e-6f);
        float cj_ = (e < TOPK) ? a14m[j * 14 + a2] * mask[j] : 0.f;
        float coef = mi[g * 16 + a1] * cj_;
        ddc[row * 200 + p] = __float2half((coef > 0.5f) ? fminf(dd, 27.f) : 40.f);
    }
    __syncthreads();   // drains vmcnt (Bs chunk 0) + lgkm (ddc/eposs)

    // ---- main loop setup ----
    const int l16 = lane & 15, lk = lane >> 4;
    const int mh = wave >> 1, nh = wave & 1;
    const int r0 = 8 * (lk & 1);
    const float mu0 = (float)r0 * 1.33333333f;
    float wc[7];
    #pragma unroll
    for (int j = 1; j < 8; ++j)
        wc[j - 1] = __expf(-1.13777778f * (float)(2 * (r0 + j) - 1));

    int boff[2][4];
    #pragma unroll
    for (int ks = 0; ks < 2; ++ks)
        #pragma unroll
        for (int nf = 0; nf < 4; ++nf) {
            int n = nh * 64 + nf * 16 + l16;
            boff[ks][nf] = n * 64 + ((((ks << 2) | lk) ^ (n & 7)) << 3);
        }
    int doff[2], eoff[2];
    #pragma unroll
    for (int mf = 0; mf < 2; ++mf) {
        int row = mh * 32 + mf * 16 + l16;
        doff[mf] = row * 200;
        eoff[mf] = row * 16 + r0;
    }

    f32x4 acc[2][4] = {};

    for (int ch = 0; ch < NCHUNK; ++ch) {
        // 1. B fragments from LDS (swizzled; Bs holds chunk ch)
        bf16x8 bfr[2][4];
        #pragma unroll
        for (int ks = 0; ks < 2; ++ks)
            #pragma unroll
            for (int nf = 0; nf < 4; ++nf)
                bfr[ks][nf] = *(const bf16x8*)&Bs[boff[ks][nf]];
        // 2. barrier: all waves' reads done (compiler drains lgkm first)
        __syncthreads();
        // 3. stage next chunk into the (now-free) single buffer
        if (ch + 1 < NCHUNK) {
            #pragma unroll
            for (int it = 0; it < 4; ++it)
                ASYNC16(Bs + wave * 2048 + it * 512,
                        gsrc + (size_t)it * 8 * KPAD + (ch + 1) * 64);
        }
        // 4. A fragments in registers (exp2-form chain, cvt_pk packing)
        bf16x8 af[2][2];
        #pragma unroll
        for (int ks = 0; ks < 2; ++ks) {
            const int p = 4 * ch + 2 * ks + (lk >> 1) - 1;
            #pragma unroll
            for (int mf = 0; mf < 2; ++mf) {
                if (p < 0) {
                    af[ks][mf] = *(const bf16x8*)&eposs[eoff[mf]];
                } else if (p < 196) {
                    float dd = __half2float(ddc[doff[mf] + p]);
                    float w = fexp2(dd * 2.46219921f);        // exp(1.70667*dd)
                    float s = dd - mu0;
                    float ev[8];
                    ev[0] = fexp2(s * s * -0.92332483f);      // exp(-(0.8 s)^2)
                    #pragma unroll
                    for (int j = 1; j < 8; ++j) ev[j] = ev[j - 1] * w * wc[j - 1];
                    union { unsigned u[4]; bf16x8 v; } o;
                    #pragma unroll
                    for (int j = 0; j < 4; ++j)
                        o.u[j] = cvt_pk_bf16(ev[2 * j], ev[2 * j + 1]);
                    af[ks][mf] = o.v;
                } else {
                    af[ks][mf] = (bf16x8){0, 0, 0, 0, 0, 0, 0, 0};
                }
            }
        }
        // 5. MFMA (fragments all in regs)
        #pragma unroll
        for (int ks = 0; ks < 2; ++ks)
            #pragma unroll
            for (int mf = 0; mf < 2; ++mf)
                #pragma unroll
                for (int nf = 0; nf < 4; ++nf)
                    acc[mf][nf] = __builtin_amdgcn_mfma_f32_16x16x32_bf16(
                        af[ks][mf], bfr[ks][nf], acc[mf][nf], 0, 0, 0);
        // 6. barrier: drains vmcnt -> Bs holds chunk ch+1
        __syncthreads();
    }

    // ---- LayerNorm epilogue (C/D: col = lane&15, row = (lane>>4)*4+reg) ----
    #pragma unroll
    for (int mf = 0; mf < 2; ++mf)
        #pragma unroll
        for (int reg = 0; reg < 4; ++reg) {
            float s = acc[mf][0][reg] + acc[mf][1][reg] + acc[mf][2][reg] + acc[mf][3][reg];
            float q = acc[mf][0][reg] * acc[mf][0][reg] + acc[mf][1][reg] * acc[mf][1][reg]
                    + acc[mf][2][reg] * acc[mf][2][reg] + acc[mf][3][reg] * acc[mf][3][reg];
            #pragma unroll
            for (int m = 1; m < 16; m <<= 1) {
                s += __shfl_xor(s, m);
                q += __shfl_xor(q, m);
            }
            if (l16 == 0) {
                int row = mh * 32 + mf * 16 + lk * 4 + reg;
                lnS[row * 2 + nh] = s;
                lnQ[row * 2 + nh] = q;
            }
        }
    __syncthreads();

    float gl[4], bl[4];
    #pragma unroll
    for (int nf = 0; nf < 4; ++nf) {
        int col = nh * 64 + nf * 16 + l16;
        gl[nf] = gamma[col];
        bl[nf] = beta[col];
    }
    #pragma unroll
    for (int mf = 0; mf < 2; ++mf)
        #pragma unroll
        for (int reg = 0; reg < 4; ++reg) {
            int r = mh * 32 + mf * 16 + lk * 4 + reg;
            int e = r & 31, g = r >> 5;
            if (e < TOPK) {
                float s = lnS[r * 2 + 0] + lnS[r * 2 + 1];
                float q = lnQ[r * 2 + 0] + lnQ[r * 2 + 1];
                float mean = s * (1.f / 128.f);
                float var = q * (1.f / 128.f) - mean * mean;
                float inv = 1.f / sqrtf(var + 1e-5f);
                float* dst = &E[((size_t)((i0 + g) * TOPK + e)) * 128];
                #pragma unroll
                for (int nf = 0; nf < 4; ++nf) {
                    int col = nh * 64 + nf * 16 + l16;
                    dst[col] = (acc[mf][nf][reg] - mean) * inv * gl[nf] + bl[nf];
                }
            }
        }
}

// ---------------------------------------------------------------------------
extern "C" void kernel_launch(void* const* d_in, const int* in_sizes, int n_in,
                              void* d_out, int out_size, void* d_ws, size_t ws_size,
                              hipStream_t stream)
{
    const float* x       = (const float*)d_in[0];
    const float* mask    = (const float*)d_in[1];
    const float* a14m    = (const float*)d_in[2];
    const float* feat    = (const float*)d_in[3];
    const float* W_pos   = (const float*)d_in[4];
    const float* b_pos   = (const float*)d_in[5];
    const float* W_edge  = (const float*)d_in[6];
    const float* gamma_e = (const float*)d_in[7];
    const float* beta_e  = (const float*)d_in[8];
    const float* W_node  = (const float*)d_in[9];
    const float* gamma_n = (const float*)d_in[10];
    const float* beta_n  = (const float*)d_in[11];
    const int*   S       = (const int*)d_in[12];
    const int*   R_idx   = (const int*)d_in[13];
    const int*   chain   = (const int*)d_in[14];

    float* out     = (float*)d_out;
    float* V       = out;                                  // 1536*128
    float* E       = out + 196608;                         // 1536*30*128
    float* out_idx = out + 196608 + 5898240;               // 1536*30
    float* out_x   = out_idx + 46080;                      // 1536*14*3

    ushort* Wt = (ushort*)d_ws;                            // 128*3200 bf16

    prep_kernel<<<PREP_BLKS, 256, 0, stream>>>(
        x, mask, feat, W_edge, Wt, W_node, gamma_n, beta_n, S, V, out_idx, out_x);
    edge_mfma_kernel<<<EDGE_BLKS, 256, 0, stream>>>(
        x, mask, a14m, W_pos, b_pos, Wt, gamma_e, beta_e, R_idx, chain,
        out_idx, E);
}